// Round 13
// baseline (31.002 us; speedup 1.0000x reference)
//
#include <hip/hip_runtime.h>
#include <hip/hip_fp16.h>

#define SCALE (1.0f/16.0f)

typedef __attribute__((ext_vector_type(8))) _Float16 f16x8;
typedef __attribute__((ext_vector_type(4))) float f32x4;
typedef __attribute__((ext_vector_type(16))) float f32x16;
typedef __attribute__((ext_vector_type(4))) unsigned int u32x4;
typedef unsigned int u32;

// keep 16 u32x4 W-fragments alive in VGPRs (prevents load sinking past barrier)
#define PIN16(W) { _Pragma("unroll") \
    for (int s_ = 0; s_ < 16; ++s_) \
        asm volatile("" : "+v"((W)[s_][0]), "+v"((W)[s_][1]), "+v"((W)[s_][2]), "+v"((W)[s_][3])); }

__device__ __forceinline__ void gload16(const void* g, void* l) {
    __builtin_amdgcn_global_load_lds(
        (const __attribute__((address_space(1))) unsigned int*)g,
        (__attribute__((address_space(3))) unsigned int*)l, 16, 0, 0);
}
__device__ __forceinline__ __half2 asH2(u32 v) {
    union { u32 i; __half2 h; } u; u.i = v; return u.h;
}
__device__ __forceinline__ u32 asU32(__half2 h) {
    union { __half2 h; u32 i; } u; u.h = h; return u.i;
}
__device__ __forceinline__ int dupH2(float f) {
    __half h = __float2half_rn(f);
    __half2 d; d.x = h; d.y = h;
    union { __half2 h2; int i; } u; u.h2 = d; return u.i;
}

// ---------------- K1: prep = transpose (blocks 0..255) + permw (blocks 256..511) ----------------
__global__ void k_prep(const float* __restrict__ feat, __half* __restrict__ featT,
                       const float* __restrict__ wf, __half* __restrict__ wr) {
    __shared__ float t[64][65];
    int b = blockIdx.x;
    if (b < 256) {
        int cb = (b >> 6) << 6;
        int pb = (b & 63) << 6;
        int lx = threadIdx.x & 63, ly = threadIdx.x >> 6;
#pragma unroll
        for (int i = 0; i < 16; ++i) {
            int cl = i*4 + ly;
            t[cl][lx] = feat[(size_t)(cb + cl) * 4096 + pb + lx];
        }
        __syncthreads();
#pragma unroll
        for (int i = 0; i < 16; ++i) {
            int pl = i*4 + ly;
            featT[(size_t)(pb + pl) * 256 + cb + lx] = __float2half_rn(t[lx][pl]);
        }
    } else {
        int ch = (b - 256) * 256 + threadIdx.x;   // 65536 chunks
        int l  = ch & 63;
        int sk = (ch >> 6) & 15;
        int ot = (ch >> 10) & 7;
        int j  = ch >> 13;
        int o = ot*32 + (l & 31);
        int k = j*256 + sk*16 + (l >> 5)*8;
        const float* src = wf + (size_t)o*2048 + k;
        f32x4 a = *(const f32x4*)src;
        f32x4 bb = *(const f32x4*)(src + 4);
        f16x8 p;
#pragma unroll
        for (int u = 0; u < 4; ++u) p[u] = (_Float16)a[u];
#pragma unroll
        for (int u = 0; u < 4; ++u) p[4+u] = (_Float16)bb[u];
        *((f16x8*)wr + ch) = p;
    }
}

// ---------------- K2: fused ROIAlign + GEMM, pinned W prefetch + split-K waves ----------------
// Grid 256: (n 0..127, hh 0..1). 512 thr = 8 waves = (oq 0..3) x (kh 0..1).
// Wave computes o-tiles {2oq, 2oq+1} over its K-half; split-K reduced in epilogue.
__global__ void __launch_bounds__(512) k_fused(
    const __half* __restrict__ featT,
    const float* __restrict__ boxes,
    const __half* __restrict__ wr,
    const float* __restrict__ bfuse,
    float* __restrict__ out)
{
    __shared__ char patch[2][32768];     // [buf][y 8][px 8][c 256] fp16
    __shared__ char Pl[2][16384];        // [buf][32 hw][256 c] fp16, XOR-swizzled
    __shared__ int4 tabs[4][2][7];       // [box&3][x/y][idx]
    __shared__ int  pbs[4][2];           // [box&3][xb, yb]

    int tid = threadIdx.x;
    int lane = tid & 63, wid = tid >> 6;     // 8 waves
    int r31 = lane & 31, l5 = lane >> 5;
    int oq = wid & 3, kh = wid >> 2;
    int bid = blockIdx.x;
    int n  = bid & 127;
    int hh = bid >> 7;
    int HWn = hh ? 17 : 32;

    int nb_base = (n & 15) * 8;
    int off = n >> 4;
    int t3 = off + (off >= 4 ? 1 : 0);
    int ci = t3 / 3, cj = t3 - ci*3;

    f32x16 acc0, acc1;
#pragma unroll
    for (int i = 0; i < 16; ++i) { acc0[i] = 0.f; acc1[i] = 0.f; }

    // ---- 3-tap table builder ----
    auto tablesW = [&](int jj, int isy, bool active) {
        if (active) {
            int nbx = nb_base + jj;
            float bx1 = boxes[nbx*4+0], by1 = boxes[nbx*4+1];
            float bx2 = boxes[nbx*4+2], by2 = boxes[nbx*4+3];
            float w3 = (bx2-bx1)*(1.f/3.f), h3 = (by2-by1)*(1.f/3.f);
            float org  = isy ? (by1 + ci*h3)*SCALE - 0.5f : (bx1 + cj*w3)*SCALE - 0.5f;
            float step = (isy ? h3 : w3) * (SCALE*(1.f/14.f));
            float sc = isy ? 0.25f : 1.f;
            float p = org + ((float)lane + 0.5f)*step;
            float pc = fminf(fmaxf(p, 0.f), 63.f);
            float fl = fminf(floorf(pc), 62.f);
            float fr = pc - fl;
            float c0 = __shfl(fl, 2*lane);
            float c1 = __shfl(fl, 2*lane+1);
            float f  = __shfl(fr, 2*lane);
            float f2 = __shfl(fr, 2*lane+1);
            float fl0 = __shfl(fl, 0);
            int base = min((int)fl0, 56);
            float d = c1 - c0;
            float a0 = sc*((1.f-f) + (1.f-d)*(1.f-f2));
            float a1 = sc*(f + (1.f-d)*f2 + d*(1.f-f2));
            float a2 = sc*(d*f2);
            if (lane < 7) {
                int4 e;
                e.x = (int)c0 - base;
                e.y = dupH2(a0); e.z = dupH2(a1); e.w = dupH2(a2);
                tabs[jj & 3][isy][lane] = e;
            }
            if (lane == 0) pbs[jj & 3][isy] = base;
        }
    };

    // ---- stage 8x8 px patch of box jj into patch[jj&1] ----
    auto patchStage = [&](int jj) {
        int xb = pbs[jj & 3][0], yb = pbs[jj & 3][1];
        const __half* src = featT + ((size_t)((yb + wid)*64 + xb))*256 + lane*8;
        char* dst = patch[jj & 1] + wid*4096;
#pragma unroll
        for (int seg = 0; seg < 4; ++seg)
            gload16(src + seg*512, dst + seg*1024);
    };

    // ---- pool box jj from patch[jj&1] -> Pl[jj&1] ----
    auto pool = [&](int jj) {
        int buf = jj & 1;
        int co = tid & 31;
        int e0 = tid >> 5;
        const char* pb = patch[buf] + co*16;
        for (int e = e0; e < HWn; e += 16) {
            int g = hh*32 + e;
            int h = (g*37) >> 8, w = g - h*7;
            int4 tx = tabs[jj & 3][0][w], ty = tabs[jj & 3][1][h];
            int px0 = tx.x, py0 = ty.x;
            int lx2 = min(px0 + 2, 7), ly2 = min(py0 + 2, 7);
            const char* r0 = pb + (py0*8 + px0)*512;
            const char* r1 = pb + (min(py0+1,7)*8 + px0)*512;
            const char* r2 = pb + (ly2*8 + px0)*512;
            int dx2 = (lx2 - px0)*512;
            u32x4 F00 = *(const u32x4*)(r0);
            u32x4 F01 = *(const u32x4*)(r0 + 512);
            u32x4 F02 = *(const u32x4*)(r0 + dx2);
            u32x4 F10 = *(const u32x4*)(r1);
            u32x4 F11 = *(const u32x4*)(r1 + 512);
            u32x4 F12 = *(const u32x4*)(r1 + dx2);
            u32x4 F20 = *(const u32x4*)(r2);
            u32x4 F21 = *(const u32x4*)(r2 + 512);
            u32x4 F22 = *(const u32x4*)(r2 + dx2);
            __half2 xa = asH2(tx.y), xb2 = asH2(tx.z), xc = asH2(tx.w);
            __half2 ya = asH2(ty.y), yb2 = asH2(ty.z), yc = asH2(ty.w);
            u32x4 res;
#pragma unroll
            for (int s = 0; s < 4; ++s) {
                __half2 q0 = __hfma2(asH2(F02[s]), xc, __hfma2(asH2(F01[s]), xb2, __hmul2(asH2(F00[s]), xa)));
                __half2 q1 = __hfma2(asH2(F12[s]), xc, __hfma2(asH2(F11[s]), xb2, __hmul2(asH2(F10[s]), xa)));
                __half2 q2 = __hfma2(asH2(F22[s]), xc, __hfma2(asH2(F21[s]), xb2, __hmul2(asH2(F20[s]), xa)));
                res[s] = asU32(__hfma2(q2, yc, __hfma2(q1, yb2, __hmul2(q0, ya))));
            }
            *(u32x4*)(Pl[buf] + e*512 + ((co*16) ^ ((e & 7) << 4))) = res;
        }
    };

    // ---- W register double-buffer (u32x4, pinned) ----
    u32x4 WfA[16], WfB[16];
    auto prefW = [&](u32x4* dst, int j) {
#pragma unroll
        for (int t = 0; t < 2; ++t) {
            int ot = oq*2 + t;
            const u32x4* wb = (const u32x4*)wr + ((size_t)((j*8 + ot)*16 + kh*8))*64 + lane;
#pragma unroll
            for (int s = 0; s < 8; ++s) dst[t*8 + s] = wb[s*64];
        }
    };

    auto gemm = [&](const u32x4* Wsrc, int j) {
        const char* plb = (j & 1) ? Pl[1] : Pl[0];
        f16x8 pf[8];
#pragma unroll
        for (int s = 0; s < 8; ++s) {
            int sk = kh*8 + s;
            int byo = r31*512 + ((sk*32 + l5*16) ^ ((r31 & 7) << 4));
            pf[s] = *(const f16x8*)(plb + byo);
        }
#pragma unroll
        for (int s = 0; s < 8; ++s) {
            acc0 = __builtin_amdgcn_mfma_f32_32x32x16_f16(
                __builtin_bit_cast(f16x8, Wsrc[s]), pf[s], acc0, 0, 0, 0);
            acc1 = __builtin_amdgcn_mfma_f32_32x32x16_f16(
                __builtin_bit_cast(f16x8, Wsrc[8 + s]), pf[s], acc1, 0, 0, 0);
        }
    };

    // ---- prologue ----
    tablesW(wid >> 1, wid & 1, wid < 6);
    __syncthreads();
    prefW(WfA, 0);
    patchStage(0);
    patchStage(1);
    PIN16(WfA);
    __syncthreads();       // drains gloads, tabs visible
    pool(0);
    __syncthreads();

#pragma unroll
    for (int j = 0; j < 8; ++j) {
        if (j < 7) prefW((j & 1) ? WfA : WfB, j+1);
        if (j < 6) patchStage(j+2);
        gemm((j & 1) ? WfB : WfA, j);
        if (j < 7) pool(j+1);
        if (j < 5) tablesW(j+3, wid, wid < 2);
        if (j < 7) { if (j & 1) { PIN16(WfA); } else { PIN16(WfB); } }
        __syncthreads();
    }

    // ---- split-K reduce (overlay on patch LDS) + epilogue ----
    float* red = (float*)&patch[0][0];   // 32 KB used: [oq*2+t][32 hw][32 o] f32, swizzled
    if (kh == 1) {
#pragma unroll
        for (int t = 0; t < 2; ++t) {
            f32x16 a = t ? acc1 : acc0;
#pragma unroll
            for (int q = 0; q < 4; ++q) {
                f32x4 v;
#pragma unroll
                for (int i = 0; i < 4; ++i) v[i] = a[q*4 + i];
                int byo = (oq*2 + t)*4096 + r31*128 + ((q*32 + l5*16) ^ ((r31 & 7) << 4));
                *(f32x4*)((char*)red + byo) = v;
            }
        }
    }
    __syncthreads();
    if (kh == 0) {
        int hw = hh*32 + r31;
        bool ok = hw < 49;
        float* ob = out + (size_t)n*12544 + hw;
#pragma unroll
        for (int t = 0; t < 2; ++t) {
            f32x16 a = t ? acc1 : acc0;
            int otb = (oq*2 + t)*32;
#pragma unroll
            for (int q = 0; q < 4; ++q) {
                int byo = (oq*2 + t)*4096 + r31*128 + ((q*32 + l5*16) ^ ((r31 & 7) << 4));
                f32x4 r = *(const f32x4*)((const char*)red + byo);
#pragma unroll
                for (int i = 0; i < 4; ++i) {
                    int o = otb + q*8 + l5*4 + i;
                    float v = a[q*4 + i] + r[i] + bfuse[o];
                    if (ok) ob[(size_t)o*49] = fmaxf(v, 0.f);
                }
            }
        }
    }
}

extern "C" void kernel_launch(void* const* d_in, const int* in_sizes, int n_in,
                              void* d_out, int out_size, void* d_ws, size_t ws_size,
                              hipStream_t stream) {
    const float* feat  = (const float*)d_in[0];   // [256,64,64]
    const float* boxes = (const float*)d_in[1];   // [128,4]
    const float* wf    = (const float*)d_in[2];   // [256,2048]
    const float* bfuse = (const float*)d_in[3];   // [256]
    float* out = (float*)d_out;                   // [128,256,7,7]

    char* ws = (char*)d_ws;
    __half* wr    = (__half*)ws;                  // 1 MB (permuted W, fp16)
    __half* featT = (__half*)(ws + (1u<<20));     // 2 MB (fp16 feat, pix-major)

    k_prep<<<512, 256, 0, stream>>>(feat, featT, wf, wr);
    k_fused<<<256, 512, 0, stream>>>(featT, boxes, wr, bfuse, out);
}